// Round 4
// baseline (1128.201 us; speedup 1.0000x reference)
//
#include <hip/hip_runtime.h>
#include <math.h>

#define D_MODEL 1024
#define SEQ     2048
#define NROWS   4096
#define LN_EPS  1e-5f

typedef __attribute__((ext_vector_type(8))) short  short8;
typedef __attribute__((ext_vector_type(4))) unsigned short ushort4v;
typedef __attribute__((ext_vector_type(4))) float  f32x4;
typedef unsigned short ushort;

#define MFMA(a,b,c) __builtin_amdgcn_mfma_f32_16x16x32_bf16(a,b,c,0,0,0)

__device__ __forceinline__ ushort bf16_rn(float x) {
    unsigned u = __float_as_uint(x);
    return (ushort)((u + 0x7FFFu + ((u >> 16) & 1u)) >> 16);
}
__device__ __forceinline__ float bf16_to_f(ushort h) {
    return __uint_as_float((unsigned)h << 16);
}

// ---------------------------------------------------------------------------
// split fp32 -> (hi, lo) bf16 pair.  x ~= hi + lo, err ~2^-18 |x|
// ---------------------------------------------------------------------------
__global__ __launch_bounds__(256)
void splitk(const float* __restrict__ x, ushort* __restrict__ hi,
            ushort* __restrict__ lo, int n4)
{
    int i = blockIdx.x * 256 + threadIdx.x;
    if (i >= n4) return;
    float4 v = *(const float4*)&x[(size_t)i * 4];
    ushort h0 = bf16_rn(v.x), h1 = bf16_rn(v.y), h2 = bf16_rn(v.z), h3 = bf16_rn(v.w);
    ushort l0 = bf16_rn(v.x - bf16_to_f(h0));
    ushort l1 = bf16_rn(v.y - bf16_to_f(h1));
    ushort l2 = bf16_rn(v.z - bf16_to_f(h2));
    ushort l3 = bf16_rn(v.w - bf16_to_f(h3));
    ushort4v h = {h0, h1, h2, h3}, l = {l0, l1, l2, l3};
    *(ushort4v*)&hi[(size_t)i * 4] = h;
    *(ushort4v*)&lo[(size_t)i * 4] = l;
}

// ---------------------------------------------------------------------------
// C = (A @ W^T + bias) * scale  [+ res]  via bf16x3 MFMA.
// A: either fp32 (Af) split on the fly, or pre-split (Ahi/Alo).
// Out: either fp32 (Cf, + optional res) or split bf16 (Chi/Clo).
// 128x128 tile, BK=32, 256 thr = 4 waves (2x2 of 64x64).
// LDS rows padded to 40 ushort (80 B = 20 banks): ~2-way conflicts (free, m136).
// ---------------------------------------------------------------------------
__global__ __launch_bounds__(256, 2)
void gemm_x3(const float* __restrict__ Af,
             const ushort* __restrict__ Ahi, const ushort* __restrict__ Alo,
             const ushort* __restrict__ Whi, const ushort* __restrict__ Wlo,
             const float* __restrict__ bias, const float* __restrict__ res,
             float scale,
             float* __restrict__ Cf, ushort* __restrict__ Chi, ushort* __restrict__ Clo)
{
    __shared__ ushort Ah[128][40], Al[128][40], Bh[128][40], Bl[128][40];
    const int K = D_MODEL;
    const int tid = threadIdx.x, lane = tid & 63, wave = tid >> 6;
    const int m0 = blockIdx.y * 128, n0 = blockIdx.x * 128;
    const int wm = (wave >> 1) * 64, wn = (wave & 1) * 64;
    const int fr = lane & 15, fq = lane >> 4;
    const int sr = tid >> 1, sc = (tid & 1) * 16;

    f32x4 acc[4][4];
    #pragma unroll
    for (int i = 0; i < 4; ++i)
        #pragma unroll
        for (int j = 0; j < 4; ++j) acc[i][j] = (f32x4){0.f,0.f,0.f,0.f};

    for (int k0 = 0; k0 < K; k0 += 32) {
        __syncthreads();
        if (Af) {
            const float* ap = &Af[(size_t)(m0 + sr) * K + k0 + sc];
            #pragma unroll
            for (int i = 0; i < 4; ++i) {
                float4 v = *(const float4*)(ap + i * 4);
                ushort h0 = bf16_rn(v.x), h1 = bf16_rn(v.y), h2 = bf16_rn(v.z), h3 = bf16_rn(v.w);
                ushort l0 = bf16_rn(v.x - bf16_to_f(h0));
                ushort l1 = bf16_rn(v.y - bf16_to_f(h1));
                ushort l2 = bf16_rn(v.z - bf16_to_f(h2));
                ushort l3 = bf16_rn(v.w - bf16_to_f(h3));
                ushort4v h = {h0,h1,h2,h3}, l = {l0,l1,l2,l3};
                *(ushort4v*)&Ah[sr][sc + i*4] = h;
                *(ushort4v*)&Al[sr][sc + i*4] = l;
            }
        } else {
            const size_t ao = (size_t)(m0 + sr) * K + k0 + sc;
            *(short8*)&Ah[sr][sc]     = *(const short8*)&Ahi[ao];
            *(short8*)&Ah[sr][sc + 8] = *(const short8*)&Ahi[ao + 8];
            *(short8*)&Al[sr][sc]     = *(const short8*)&Alo[ao];
            *(short8*)&Al[sr][sc + 8] = *(const short8*)&Alo[ao + 8];
        }
        {
            const size_t wo = (size_t)(n0 + sr) * K + k0 + sc;
            *(short8*)&Bh[sr][sc]     = *(const short8*)&Whi[wo];
            *(short8*)&Bh[sr][sc + 8] = *(const short8*)&Whi[wo + 8];
            *(short8*)&Bl[sr][sc]     = *(const short8*)&Wlo[wo];
            *(short8*)&Bl[sr][sc + 8] = *(const short8*)&Wlo[wo + 8];
        }
        __syncthreads();

        short8 ah[4], al4[4], bh4[4], bl4[4];
        #pragma unroll
        for (int f = 0; f < 4; ++f) {
            ah[f]  = *(const short8*)&Ah[wm + f*16 + fr][fq * 8];
            al4[f] = *(const short8*)&Al[wm + f*16 + fr][fq * 8];
            bh4[f] = *(const short8*)&Bh[wn + f*16 + fr][fq * 8];
            bl4[f] = *(const short8*)&Bl[wn + f*16 + fr][fq * 8];
        }
        #pragma unroll
        for (int mf = 0; mf < 4; ++mf)
            #pragma unroll
            for (int nf = 0; nf < 4; ++nf) {
                acc[mf][nf] = MFMA(al4[mf], bh4[nf], acc[mf][nf]);
                acc[mf][nf] = MFMA(ah[mf],  bl4[nf], acc[mf][nf]);
                acc[mf][nf] = MFMA(ah[mf],  bh4[nf], acc[mf][nf]);
            }
    }

    #pragma unroll
    for (int mf = 0; mf < 4; ++mf)
        #pragma unroll
        for (int nf = 0; nf < 4; ++nf) {
            const int n = n0 + wn + nf*16 + fr;
            const float bn = bias[n];
            #pragma unroll
            for (int j = 0; j < 4; ++j) {
                const int m = m0 + wm + mf*16 + fq*4 + j;
                float x = (acc[mf][nf][j] + bn) * scale;
                if (Cf) {
                    if (res) x += res[(size_t)m * D_MODEL + n];
                    Cf[(size_t)m * D_MODEL + n] = x;
                } else {
                    ushort hh = bf16_rn(x);
                    ushort ll = bf16_rn(x - bf16_to_f(hh));
                    Chi[(size_t)m * D_MODEL + n] = hh;
                    Clo[(size_t)m * D_MODEL + n] = ll;
                }
            }
        }
}

// ---------------------------------------------------------------------------
// Per-head transpose of projected V: [token][emb] -> [b][h][dv][token]
// ---------------------------------------------------------------------------
__global__ __launch_bounds__(256)
void vtrans(const ushort* __restrict__ Vhi, const ushort* __restrict__ Vlo,
            ushort* __restrict__ Vthi, ushort* __restrict__ Vtlo)
{
    __shared__ ushort Th[64][72], Tl[64][72];
    const int t = threadIdx.x;
    const int t0 = blockIdx.x * 64, bh = blockIdx.y, b = bh >> 4, h = bh & 15;
    const int r = t >> 2, c = (t & 3) * 16;
    const size_t src = (size_t)(b * SEQ + t0 + r) * D_MODEL + h * 64 + c;
    short8 x0 = *(const short8*)&Vhi[src];
    short8 x1 = *(const short8*)&Vhi[src + 8];
    short8 y0 = *(const short8*)&Vlo[src];
    short8 y1 = *(const short8*)&Vlo[src + 8];
    #pragma unroll
    for (int e = 0; e < 8; ++e) {
        Th[c + e][r]     = (ushort)x0[e];
        Th[c + 8 + e][r] = (ushort)x1[e];
        Tl[c + e][r]     = (ushort)y0[e];
        Tl[c + 8 + e][r] = (ushort)y1[e];
    }
    __syncthreads();
    const size_t dst = (size_t)(bh * 64 + r) * SEQ + t0 + c;
    *(short8*)&Vthi[dst]     = *(const short8*)&Th[r][c];
    *(short8*)&Vthi[dst + 8] = *(const short8*)&Th[r][c + 8];
    *(short8*)&Vtlo[dst]     = *(const short8*)&Tl[r][c];
    *(short8*)&Vtlo[dst + 8] = *(const short8*)&Tl[r][c + 8];
}

// ---------------------------------------------------------------------------
// Fused attention (bf16x3): per (bh, 64 q-rows), two-pass online softmax.
// Pass A: stats (m,l).  Pass B: recompute, write normalized attention once,
// accumulate PV.  4 waves; wave w owns q-rows w*16..w*16+15.
// ---------------------------------------------------------------------------
__global__ __launch_bounds__(256, 2)
void attn_x3(const ushort* __restrict__ Qhi, const ushort* __restrict__ Qlo,
             const ushort* __restrict__ Khi, const ushort* __restrict__ Klo,
             const ushort* __restrict__ Vthi, const ushort* __restrict__ Vtlo,
             float* __restrict__ attn, ushort* __restrict__ PVhi, ushort* __restrict__ PVlo)
{
    __shared__ ushort Kh[64][72], Kl[64][72];
    __shared__ ushort Vh[64][72], Vl[64][72];
    __shared__ ushort Ph[4][16][72], Pl[4][16][72];

    const int tid = threadIdx.x, lane = tid & 63, wave = tid >> 6;
    const int fr = lane & 15, fq = lane >> 4;
    const int bh = blockIdx.y, b = bh >> 4, h = bh & 15;
    const int q0 = blockIdx.x * 64;
    const int sr = tid >> 2, sc = (tid & 3) * 16;

    const ushort* Khb = Khi + (size_t)(b * SEQ) * D_MODEL + h * 64;
    const ushort* Klb = Klo + (size_t)(b * SEQ) * D_MODEL + h * 64;
    const ushort* Vhb = Vthi + (size_t)(bh * 64) * SEQ;
    const ushort* Vlb = Vtlo + (size_t)(bh * 64) * SEQ;

    // Q fragments straight from global (Q pre-scaled by 1/8 in its GEMM)
    short8 qh[2], ql[2];
    #pragma unroll
    for (int kf = 0; kf < 2; ++kf) {
        const size_t qo = (size_t)(b * SEQ + q0 + wave*16 + fr) * D_MODEL + h*64 + kf*32 + fq*8;
        qh[kf] = *(const short8*)&Qhi[qo];
        ql[kf] = *(const short8*)&Qlo[qo];
    }

    float m_run[4], l_run[4];
    #pragma unroll
    for (int j = 0; j < 4; ++j) { m_run[j] = -1e30f; l_run[j] = 0.f; }

    // ---------------- Pass A: stats ----------------
    for (int kt = 0; kt < SEQ/64; ++kt) {
        __syncthreads();
        {
            const size_t src = (size_t)(kt*64 + sr) * D_MODEL + sc;
            *(short8*)&Kh[sr][sc]     = *(const short8*)&Khb[src];
            *(short8*)&Kh[sr][sc + 8] = *(const short8*)&Khb[src + 8];
            *(short8*)&Kl[sr][sc]     = *(const short8*)&Klb[src];
            *(short8*)&Kl[sr][sc + 8] = *(const short8*)&Klb[src + 8];
        }
        __syncthreads();
        f32x4 sacc[4];
        #pragma unroll
        for (int nf = 0; nf < 4; ++nf) sacc[nf] = (f32x4){0.f,0.f,0.f,0.f};
        #pragma unroll
        for (int nf = 0; nf < 4; ++nf)
            #pragma unroll
            for (int kf = 0; kf < 2; ++kf) {
                short8 kh = *(const short8*)&Kh[nf*16 + fr][kf*32 + fq*8];
                short8 kl = *(const short8*)&Kl[nf*16 + fr][kf*32 + fq*8];
                sacc[nf] = MFMA(ql[kf], kh, sacc[nf]);
                sacc[nf] = MFMA(qh[kf], kl, sacc[nf]);
                sacc[nf] = MFMA(qh[kf], kh, sacc[nf]);
            }
        #pragma unroll
        for (int j = 0; j < 4; ++j) {
            float mx = fmaxf(fmaxf(sacc[0][j], sacc[1][j]), fmaxf(sacc[2][j], sacc[3][j]));
            #pragma unroll
            for (int off = 1; off < 16; off <<= 1) mx = fmaxf(mx, __shfl_xor(mx, off));
            float mnew = fmaxf(m_run[j], mx);
            float s = __expf(sacc[0][j]-mnew) + __expf(sacc[1][j]-mnew)
                    + __expf(sacc[2][j]-mnew) + __expf(sacc[3][j]-mnew);
            #pragma unroll
            for (int off = 1; off < 16; off <<= 1) s += __shfl_xor(s, off);
            l_run[j] = l_run[j] * __expf(m_run[j] - mnew) + s;
            m_run[j] = mnew;
        }
    }

    float rl[4];
    #pragma unroll
    for (int j = 0; j < 4; ++j) rl[j] = 1.f / l_run[j];

    f32x4 pacc[4];
    #pragma unroll
    for (int nf = 0; nf < 4; ++nf) pacc[nf] = (f32x4){0.f,0.f,0.f,0.f};

    // ---------------- Pass B: write attention + PV ----------------
    for (int kt = 0; kt < SEQ/64; ++kt) {
        __syncthreads();
        {
            const size_t src = (size_t)(kt*64 + sr) * D_MODEL + sc;
            *(short8*)&Kh[sr][sc]     = *(const short8*)&Khb[src];
            *(short8*)&Kh[sr][sc + 8] = *(const short8*)&Khb[src + 8];
            *(short8*)&Kl[sr][sc]     = *(const short8*)&Klb[src];
            *(short8*)&Kl[sr][sc + 8] = *(const short8*)&Klb[src + 8];
            const size_t vsrc = (size_t)sr * SEQ + kt*64 + sc;
            *(short8*)&Vh[sr][sc]     = *(const short8*)&Vhb[vsrc];
            *(short8*)&Vh[sr][sc + 8] = *(const short8*)&Vhb[vsrc + 8];
            *(short8*)&Vl[sr][sc]     = *(const short8*)&Vlb[vsrc];
            *(short8*)&Vl[sr][sc + 8] = *(const short8*)&Vlb[vsrc + 8];
        }
        __syncthreads();
        f32x4 sacc[4];
        #pragma unroll
        for (int nf = 0; nf < 4; ++nf) sacc[nf] = (f32x4){0.f,0.f,0.f,0.f};
        #pragma unroll
        for (int nf = 0; nf < 4; ++nf)
            #pragma unroll
            for (int kf = 0; kf < 2; ++kf) {
                short8 kh = *(const short8*)&Kh[nf*16 + fr][kf*32 + fq*8];
                short8 kl = *(const short8*)&Kl[nf*16 + fr][kf*32 + fq*8];
                sacc[nf] = MFMA(ql[kf], kh, sacc[nf]);
                sacc[nf] = MFMA(qh[kf], kl, sacc[nf]);
                sacc[nf] = MFMA(qh[kf], kh, sacc[nf]);
            }
        #pragma unroll
        for (int nf = 0; nf < 4; ++nf)
            #pragma unroll
            for (int j = 0; j < 4; ++j) {
                float p = __expf(sacc[nf][j] - m_run[j]) * rl[j];
                const int qrow = q0 + wave*16 + fq*4 + j;
                attn[((size_t)bh * SEQ + qrow) * SEQ + kt*64 + nf*16 + fr] = p;
                ushort hh = bf16_rn(p);
                ushort ll = bf16_rn(p - bf16_to_f(hh));
                Ph[wave][fq*4 + j][nf*16 + fr] = hh;
                Pl[wave][fq*4 + j][nf*16 + fr] = ll;
            }
        // PV accumulate (per-wave P buffer: same-wave LDS dep, no barrier)
        #pragma unroll
        for (int kf = 0; kf < 2; ++kf) {
            short8 ph = *(const short8*)&Ph[wave][fr][kf*32 + fq*8];
            short8 pl = *(const short8*)&Pl[wave][fr][kf*32 + fq*8];
            #pragma unroll
            for (int nf = 0; nf < 4; ++nf) {
                short8 vh = *(const short8*)&Vh[nf*16 + fr][kf*32 + fq*8];
                short8 vl = *(const short8*)&Vl[nf*16 + fr][kf*32 + fq*8];
                pacc[nf] = MFMA(pl, vh, pacc[nf]);
                pacc[nf] = MFMA(ph, vl, pacc[nf]);
                pacc[nf] = MFMA(ph, vh, pacc[nf]);
            }
        }
    }

    #pragma unroll
    for (int nf = 0; nf < 4; ++nf)
        #pragma unroll
        for (int j = 0; j < 4; ++j) {
            const int qrow = q0 + wave*16 + fq*4 + j;
            const size_t o = (size_t)(b * SEQ + qrow) * D_MODEL + h*64 + nf*16 + fr;
            float x = pacc[nf][j];
            ushort hh = bf16_rn(x);
            ushort ll = bf16_rn(x - bf16_to_f(hh));
            PVhi[o] = hh; PVlo[o] = ll;
        }
}

// ---------------------------------------------------------------------------
// Row LayerNorm over 1024 cols (residual already folded in).
// ---------------------------------------------------------------------------
__global__ __launch_bounds__(256)
void ln_row(const float* __restrict__ X, const float* __restrict__ g,
            const float* __restrict__ bb, float* __restrict__ out)
{
    const int row = blockIdx.x;
    const int tid = threadIdx.x;
    __shared__ float red[4];

    float4 x = *(const float4*)&X[(size_t)row * D_MODEL + tid*4];
    float s = x.x + x.y + x.z + x.w;
    #pragma unroll
    for (int off = 1; off < 64; off <<= 1) s += __shfl_xor(s, off);
    int wid = tid >> 6, lane = tid & 63;
    if (lane == 0) red[wid] = s;
    __syncthreads();
    float mu = (red[0] + red[1] + red[2] + red[3]) * (1.f / 1024.f);

    float d0 = x.x - mu, d1 = x.y - mu, d2 = x.z - mu, d3 = x.w - mu;
    float ss = d0*d0 + d1*d1 + d2*d2 + d3*d3;
    #pragma unroll
    for (int off = 1; off < 64; off <<= 1) ss += __shfl_xor(ss, off);
    __syncthreads();
    if (lane == 0) red[wid] = ss;
    __syncthreads();
    float var = (red[0] + red[1] + red[2] + red[3]) * (1.f / 1024.f);
    float inv = rsqrtf(var + LN_EPS);

    float4 gv = *(const float4*)&g[tid*4];
    float4 bv = *(const float4*)&bb[tid*4];
    float4 o;
    o.x = d0 * inv * gv.x + bv.x;
    o.y = d1 * inv * gv.y + bv.y;
    o.z = d2 * inv * gv.z + bv.z;
    o.w = d3 * inv * gv.w + bv.w;
    *(float4*)&out[(size_t)row * D_MODEL + tid*4] = o;
}

// ---------------------------------------------------------------------------
extern "C" void kernel_launch(void* const* d_in, const int* in_sizes, int n_in,
                              void* d_out, int out_size, void* d_ws, size_t ws_size,
                              hipStream_t stream)
{
    (void)in_sizes; (void)n_in; (void)out_size; (void)ws_size;
    const float* q   = (const float*)d_in[0];
    const float* k   = (const float*)d_in[1];
    const float* v   = (const float*)d_in[2];
    const float* Wq  = (const float*)d_in[3];
    const float* bq  = (const float*)d_in[4];
    const float* Wk  = (const float*)d_in[5];
    const float* bk  = (const float*)d_in[6];
    const float* Wv  = (const float*)d_in[7];
    const float* bv  = (const float*)d_in[8];
    const float* Wo  = (const float*)d_in[9];
    const float* bo  = (const float*)d_in[10];
    const float* lng = (const float*)d_in[11];
    const float* lnb = (const float*)d_in[12];

    float* out_x    = (float*)d_out;
    float* out_attn = (float*)d_out + (size_t)NROWS * D_MODEL;

    // ---- workspace layout (bytes), total 96 MB ----
    char* w = (char*)d_ws;
    const size_t WB = (size_t)D_MODEL * D_MODEL * 2;   // 2 MB  (bf16 weight)
    const size_t QB = (size_t)NROWS * D_MODEL * 2;     // 8 MB  (bf16 activation)
    ushort* Wqhi = (ushort*)(w + 0*WB);  ushort* Wqlo = (ushort*)(w + 1*WB);
    ushort* Wkhi = (ushort*)(w + 2*WB);  ushort* Wklo = (ushort*)(w + 3*WB);
    ushort* Wvhi = (ushort*)(w + 4*WB);  ushort* Wvlo = (ushort*)(w + 5*WB);
    ushort* Wohi = (ushort*)(w + 6*WB);  ushort* Wolo = (ushort*)(w + 7*WB);
    char* base = w + 8*WB;                              // +16 MB
    ushort* Qhi = (ushort*)(base + 0*QB);  ushort* Qlo = (ushort*)(base + 1*QB);
    ushort* Khi = (ushort*)(base + 2*QB);  ushort* Klo = (ushort*)(base + 3*QB);
    ushort* Vhi = (ushort*)(base + 4*QB);  ushort* Vlo = (ushort*)(base + 5*QB);
    ushort* Vthi= (ushort*)(base + 6*QB);  ushort* Vtlo= (ushort*)(base + 7*QB);
    ushort* PVhi= (ushort*)(base + 8*QB);  ushort* PVlo= (ushort*)(base + 9*QB);
    float*  X   = (float*) (base + 6*QB);  // fp32, reuses dead Vt region after attn

    const int n4w = D_MODEL * D_MODEL / 4;
    splitk<<<dim3(n4w/256), dim3(256), 0, stream>>>(Wq, Wqhi, Wqlo, n4w);
    splitk<<<dim3(n4w/256), dim3(256), 0, stream>>>(Wk, Wkhi, Wklo, n4w);
    splitk<<<dim3(n4w/256), dim3(256), 0, stream>>>(Wv, Wvhi, Wvlo, n4w);
    splitk<<<dim3(n4w/256), dim3(256), 0, stream>>>(Wo, Wohi, Wolo, n4w);

    dim3 gg(D_MODEL/128, NROWS/128), gb(256);
    // Q projection, pre-scaled by 1/sqrt(Dk)=1/8 (exact in bf16)
    gemm_x3<<<gg, gb, 0, stream>>>(q, nullptr, nullptr, Wqhi, Wqlo, bq, nullptr,
                                   0.125f, nullptr, Qhi, Qlo);
    gemm_x3<<<gg, gb, 0, stream>>>(k, nullptr, nullptr, Wkhi, Wklo, bk, nullptr,
                                   1.0f, nullptr, Khi, Klo);
    gemm_x3<<<gg, gb, 0, stream>>>(v, nullptr, nullptr, Wvhi, Wvlo, bv, nullptr,
                                   1.0f, nullptr, Vhi, Vlo);

    vtrans<<<dim3(SEQ/64, 32), dim3(256), 0, stream>>>(Vhi, Vlo, Vthi, Vtlo);

    attn_x3<<<dim3(SEQ/64, 32), dim3(256), 0, stream>>>(Qhi, Qlo, Khi, Klo,
                                                        Vthi, Vtlo,
                                                        out_attn, PVhi, PVlo);

    // O projection + bias + residual(q) -> X (fp32)
    gemm_x3<<<gg, gb, 0, stream>>>(nullptr, PVhi, PVlo, Wohi, Wolo, bo, q,
                                   1.0f, X, nullptr, nullptr);

    ln_row<<<dim3(NROWS), dim3(256), 0, stream>>>(X, lng, lnb, out_x);
}